// Round 5
// baseline (595.216 us; speedup 1.0000x reference)
//
#include <hip/hip_runtime.h>

typedef unsigned short u16;
typedef __bf16 bf16x8 __attribute__((ext_vector_type(8)));
typedef float f32x4 __attribute__((ext_vector_type(4)));
typedef unsigned short u16x8 __attribute__((ext_vector_type(8)));
typedef unsigned short u16x4 __attribute__((ext_vector_type(4)));

#define MFMA16(A,B,C) __builtin_amdgcn_mfma_f32_16x16x32_bf16(A,B,C,0,0,0)

__device__ __forceinline__ float b2f(u16 h){ unsigned u = ((unsigned)h)<<16; return __builtin_bit_cast(float,u); }
__device__ __forceinline__ u16 f2b(float f){ unsigned u = __builtin_bit_cast(unsigned,f); u += 0x7fffu + ((u>>16)&1u); return (u16)(u>>16); }
__device__ __forceinline__ bf16x8 ldb8(const u16* p){ return __builtin_bit_cast(bf16x8, *(const u16x8*)p); }

// B=16, C=256, H=W=64, NH=8, DH=64, POS_C=4.  4096 px/batch.
// ALL inputs fp32 (per reference dtypes); output fp32.  bf16 only for MFMA
// staging + internal scratch.  CB batches/chunk chosen from ws_size.
// Per-batch ws: Q,K,V,U (4 x 4 MiB bf16, [bl][h][p][d]) + fp32 m,l
// (2 x 128 KiB) = 17.04 MB.  Fixed: WP/WPOS/BIAS bf16 canonical = 0.8 MB.

// ---------------------------------------------------------------------------
// Canonicalize weights to bf16: WP[1536][256], WPOS[1536][4], BIAS[1536].
__global__ void k_prep_w(const float* __restrict__ Wq, const float* __restrict__ Wk,
                         const float* __restrict__ Wv, const float* __restrict__ bq,
                         const float* __restrict__ bk, const float* __restrict__ bv,
                         u16* __restrict__ WP, u16* __restrict__ WPOS,
                         u16* __restrict__ BIAS){
  int r = blockIdx.x;                 // 0..1535
  int t = r >> 9, rm = r & 511;
  const float* src = (t==0 ? Wq : (t==1 ? Wk : Wv)) + (long)rm*260;
  int tid = threadIdx.x;
  WP[(long)r*256 + tid] = f2b(src[tid]);
  if (tid < 4) WPOS[r*4 + tid] = f2b(src[256 + tid]);
  if (tid == 0){
    const float* bs = (t==0 ? bq : (t==1 ? bk : bv));
    BIAS[r] = f2b(bs[rm]);
  }
}

// Diagnostic: ws too small -> fill out with 100.0f.
__global__ void k_sentinel(float* __restrict__ out){
  long i = (long)blockIdx.x*256 + threadIdx.x;
  out[i] = 100.0f;
}

// ---------------------------------------------------------------------------
// QKV projection GEMM: M=1536 (oc), N=CB*4096 (px), K=256 (+pos rank-4 epi).
// x (fp32, [gb][c][p]) is converted+transposed on the fly during staging.
__global__ __launch_bounds__(256) void k_qkv(
    const float* __restrict__ x, const u16* __restrict__ WP,
    const u16* __restrict__ WPOS, const float* __restrict__ pos,
    const u16* __restrict__ BIAS,
    u16* __restrict__ Qb, u16* __restrict__ Kb, u16* __restrict__ Vb,
    int b0){
  __shared__ u16 sW[128*40];   // [oc_r][c], stride 40
  __shared__ u16 sX[128*40];   // [px_r][c]
  __shared__ u16 sPW[512];     // [oc_r][4]
  __shared__ u16 sPP[512];     // [c][128]
  int bidx = blockIdx.x;
  int mt = bidx % 12; long nt = bidx / 12;
  int oc0 = mt*128; long p0 = nt*128;           // chunk-local pixel
  int bl = (int)(p0>>12); int pl0 = (int)(p0 & 4095);
  int gb = b0 + bl;
  int tid = threadIdx.x;
  for (int k = tid; k < 512; k += 256) sPW[k] = WPOS[(long)oc0*4 + k];
  for (int k = tid; k < 512; k += 256){ int c = k>>7, p = k&127; sPP[k] = f2b(pos[(long)c*4096 + pl0 + p]); }
  f32x4 zf = {0.f,0.f,0.f,0.f};
  f32x4 acc[4][4];
  #pragma unroll
  for (int i=0;i<4;++i){
    #pragma unroll
    for (int j=0;j<4;++j) acc[i][j] = zf;
  }
  int wid = tid>>6, lane = tid&63, l16 = lane&15, qd = lane>>4;
  int wm = wid>>1, wn = wid&1;
  for (int kk = 0; kk < 256; kk += 32){
    __syncthreads();
    #pragma unroll
    for (int ps=0; ps<2; ++ps){
      int idx = ps*256 + tid;
      // sW: bf16 canonical weights, vector copy
      int r = idx>>2, c8 = (idx&3)*8;
      *(u16x8*)&sW[r*40 + c8] = *(const u16x8*)&WP[(long)(oc0+r)*256 + kk + c8];
      // sX: channel cl (0..31), pixels px8..px8+7 from fp32 x, transposed
      int cl = idx>>4, px8 = (idx&15)*8;
      const float* xp = &x[((long)(gb*256 + kk + cl))*4096 + pl0 + px8];
      f32x4 v0 = *(const f32x4*)xp;
      f32x4 v1 = *(const f32x4*)(xp+4);
      #pragma unroll
      for (int u=0;u<4;++u){
        sX[(px8+u)*40 + cl]   = f2b(v0[u]);
        sX[(px8+4+u)*40 + cl] = f2b(v1[u]);
      }
    }
    __syncthreads();
    bf16x8 a[4], bb[4];
    #pragma unroll
    for (int mi=0;mi<4;++mi) a[mi]  = ldb8(&sW[(wm*64+mi*16+l16)*40 + qd*8]);
    #pragma unroll
    for (int ni=0;ni<4;++ni) bb[ni] = ldb8(&sX[(wn*64+ni*16+l16)*40 + qd*8]);
    #pragma unroll
    for (int mi=0;mi<4;++mi){
      #pragma unroll
      for (int ni=0;ni<4;++ni)
        acc[mi][ni] = MFMA16(a[mi], bb[ni], acc[mi][ni]);
    }
  }
  #pragma unroll
  for (int mi=0;mi<4;++mi){
    int mbase = wm*64 + mi*16 + qd*4;
    int ocb = oc0 + mbase;
    int t = ocb>>9, ocm = ocb&511;
    int hh = ocm>>6, dd = ocm&63;
    u16* dstb = (t==0? Qb : (t==1? Kb : Vb));
    #pragma unroll
    for (int ni=0;ni<4;++ni){
      int n = wn*64 + ni*16 + l16;
      int pl = pl0 + n;
      u16x4 pk;
      #pragma unroll
      for (int r=0;r<4;++r){
        float v = acc[mi][ni][r];
        #pragma unroll
        for (int c=0;c<4;++c) v += b2f(sPW[(mbase+r)*4+c]) * b2f(sPP[c*128 + n]);
        v += b2f(BIAS[ocb + r]);
        pk[r] = f2b(v);
      }
      *(u16x4*)&dstb[((long)(bl*8+hh)*4096 + pl)*64 + dd] = pk;
    }
  }
}

// ---------------------------------------------------------------------------
// Row pass: block (bl,h,i).  Writes unnormalized U = sum_k exp(s-m) V and
// fp32 stats m,l.
__global__ __launch_bounds__(256) void k_attn_row(
    const u16* __restrict__ Qb, const u16* __restrict__ Kb,
    const u16* __restrict__ Vb, u16* __restrict__ U,
    float* __restrict__ M, float* __restrict__ L){
  __shared__ u16 sm[4*64*72];
  u16* Qs = sm;            // [line][d]  stride 72
  u16* Ks = sm + 4608;
  u16* VT = sm + 9216;     // [d][line]
  u16* Ps = sm + 13824;    // [q][k]
  int bid = blockIdx.x;
  int rc = bid&63, h=(bid>>6)&7, bl=bid>>9;
  long plane = (long)(bl*8+h)*4096*64;
  long sbase = (long)(bl*8+h)*4096;
  int tid = threadIdx.x;
  #pragma unroll
  for (int it=0; it<2; ++it){
    int idx = it*256 + tid; int row = idx>>3, d0 = (idx&7)*8;
    long ga = plane + ((long)(rc*64 + row))*64 + d0;
    *(u16x8*)&Qs[row*72 + d0] = *(const u16x8*)&Qb[ga];
    *(u16x8*)&Ks[row*72 + d0] = *(const u16x8*)&Kb[ga];
    u16x8 vv = *(const u16x8*)&Vb[ga];
    #pragma unroll
    for (int u=0;u<8;++u) VT[(d0+u)*72 + row] = vv[u];
  }
  __syncthreads();
  int wid = tid>>6, lane = tid&63, l16 = lane&15, qd = lane>>4;
  int j0 = wid*16;
  f32x4 zf = {0.f,0.f,0.f,0.f};
  f32x4 sv[4] = {zf,zf,zf,zf};
  #pragma unroll
  for (int d0=0; d0<64; d0+=32){
    bf16x8 a = ldb8(&Qs[(j0+l16)*72 + d0 + qd*8]);
    #pragma unroll
    for (int n=0;n<4;++n){
      bf16x8 bb = ldb8(&Ks[(n*16+l16)*72 + d0 + qd*8]);
      sv[n] = MFMA16(a, bb, sv[n]);
    }
  }
  const float scale = 0.08838834764831845f;   // 1/sqrt(128)
  float mrow[4], lrow[4];
  #pragma unroll
  for (int r=0;r<4;++r){
    float mv = -1e30f;
    #pragma unroll
    for (int n=0;n<4;++n){ sv[n][r] *= scale; mv = fmaxf(mv, sv[n][r]); }
    mv = fmaxf(mv, __shfl_xor(mv,1)); mv = fmaxf(mv, __shfl_xor(mv,2));
    mv = fmaxf(mv, __shfl_xor(mv,4)); mv = fmaxf(mv, __shfl_xor(mv,8));
    float ls = 0.f;
    #pragma unroll
    for (int n=0;n<4;++n){ float p = expf(fminf(sv[n][r]-mv, 0.f)); sv[n][r] = p; ls += p; }
    ls += __shfl_xor(ls,1); ls += __shfl_xor(ls,2);
    ls += __shfl_xor(ls,4); ls += __shfl_xor(ls,8);
    mrow[r]=mv; lrow[r]=ls;
    int qi = j0 + qd*4 + r;
    #pragma unroll
    for (int n=0;n<4;++n) Ps[qi*72 + n*16 + l16] = f2b(sv[n][r]);
  }
  __syncthreads();
  f32x4 u4[4] = {zf,zf,zf,zf};
  #pragma unroll
  for (int k0=0;k0<64;k0+=32){
    bf16x8 a = ldb8(&Ps[(j0+l16)*72 + k0 + qd*8]);
    #pragma unroll
    for (int n=0;n<4;++n){
      bf16x8 bb = ldb8(&VT[(n*16+l16)*72 + k0 + qd*8]);
      u4[n] = MFMA16(a, bb, u4[n]);
    }
  }
  #pragma unroll
  for (int r=0;r<4;++r){
    int qi = j0 + qd*4 + r;
    long pl = (long)rc*64 + qi;
    long ob = (sbase + pl)*64;
    #pragma unroll
    for (int n=0;n<4;++n) U[ob + n*16 + l16] = f2b(u4[n][r]);
    if (l16==0){ M[sbase+pl]=mrow[r]; L[sbase+pl]=lrow[r]; }
  }
}

// ---------------------------------------------------------------------------
// Column pass + merge: block (bl,h,j).  Computes column stats in-register,
// reads U/m/l, flash-merges, overwrites U with final A.
__global__ __launch_bounds__(256) void k_attn_col(
    const u16* __restrict__ Qb, const u16* __restrict__ Kb,
    const u16* __restrict__ Vb, u16* __restrict__ U,
    const float* __restrict__ M, const float* __restrict__ L){
  __shared__ u16 sm[4*64*72];
  u16* Qs = sm;
  u16* Ks = sm + 4608;
  u16* VT = sm + 9216;
  u16* Ps = sm + 13824;
  int bid = blockIdx.x;
  int rc = bid&63, h=(bid>>6)&7, bl=bid>>9;
  long plane = (long)(bl*8+h)*4096*64;
  long sbase = (long)(bl*8+h)*4096;
  int tid = threadIdx.x;
  #pragma unroll
  for (int it=0; it<2; ++it){
    int idx = it*256 + tid; int row = idx>>3, d0 = (idx&7)*8;
    long ga = plane + ((long)(row*64 + rc))*64 + d0;
    *(u16x8*)&Qs[row*72 + d0] = *(const u16x8*)&Qb[ga];
    *(u16x8*)&Ks[row*72 + d0] = *(const u16x8*)&Kb[ga];
    u16x8 vv = *(const u16x8*)&Vb[ga];
    #pragma unroll
    for (int u=0;u<8;++u) VT[(d0+u)*72 + row] = vv[u];
  }
  __syncthreads();
  int wid = tid>>6, lane = tid&63, l16 = lane&15, qd = lane>>4;
  int j0 = wid*16;
  f32x4 zf = {0.f,0.f,0.f,0.f};
  f32x4 sv[4] = {zf,zf,zf,zf};
  #pragma unroll
  for (int d0=0; d0<64; d0+=32){
    bf16x8 a = ldb8(&Qs[(j0+l16)*72 + d0 + qd*8]);
    #pragma unroll
    for (int n=0;n<4;++n){
      bf16x8 bb = ldb8(&Ks[(n*16+l16)*72 + d0 + qd*8]);
      sv[n] = MFMA16(a, bb, sv[n]);
    }
  }
  const float scale = 0.08838834764831845f;
  float mrow[4], lrow[4];
  #pragma unroll
  for (int r=0;r<4;++r){
    float mv = -1e30f;
    #pragma unroll
    for (int n=0;n<4;++n){ sv[n][r] *= scale; mv = fmaxf(mv, sv[n][r]); }
    mv = fmaxf(mv, __shfl_xor(mv,1)); mv = fmaxf(mv, __shfl_xor(mv,2));
    mv = fmaxf(mv, __shfl_xor(mv,4)); mv = fmaxf(mv, __shfl_xor(mv,8));
    float ls = 0.f;
    #pragma unroll
    for (int n=0;n<4;++n){ float p = expf(fminf(sv[n][r]-mv, 0.f)); sv[n][r] = p; ls += p; }
    ls += __shfl_xor(ls,1); ls += __shfl_xor(ls,2);
    ls += __shfl_xor(ls,4); ls += __shfl_xor(ls,8);
    mrow[r]=mv; lrow[r]=ls;
    int qi = j0 + qd*4 + r;
    #pragma unroll
    for (int n=0;n<4;++n) Ps[qi*72 + n*16 + l16] = f2b(sv[n][r]);
  }
  __syncthreads();
  f32x4 u4[4] = {zf,zf,zf,zf};
  #pragma unroll
  for (int k0=0;k0<64;k0+=32){
    bf16x8 a = ldb8(&Ps[(j0+l16)*72 + k0 + qd*8]);
    #pragma unroll
    for (int n=0;n<4;++n){
      bf16x8 bb = ldb8(&VT[(n*16+l16)*72 + k0 + qd*8]);
      u4[n] = MFMA16(a, bb, u4[n]);
    }
  }
  #pragma unroll
  for (int r=0;r<4;++r){
    int qi = j0 + qd*4 + r;
    long pix = sbase + (long)qi*64 + rc;
    float mw = M[pix], lw = L[pix];
    float mh = mrow[r], lh = lrow[r];
    float m  = fmaxf(mw, mh);
    float ew = expf(fminf(mw - m, 0.f));
    float eh = expf(fminf(mh - m, 0.f));
    float rden = 1.f / fmaxf(ew*lw + eh*lh, 1e-20f);
    long ob = pix*64;
    #pragma unroll
    for (int n=0;n<4;++n){
      float uw = b2f(U[ob + n*16 + l16]);
      U[ob + n*16 + l16] = f2b((ew*uw + eh*u4[n][r])*rden);
    }
  }
}

// ---------------------------------------------------------------------------
// Output projection + residual: out = x + Wo @ A + bo (all fp32 I/O).
// A in U [bl][h][p][d] (bf16).  M=256 (co), N=CB*4096 (px), K=512.
__global__ __launch_bounds__(256) void k_oproj(
    const float* __restrict__ Wo, const float* __restrict__ bo,
    const u16* __restrict__ AC, const float* __restrict__ x,
    float* __restrict__ out, int b0){
  __shared__ u16 sW[128*40];
  __shared__ u16 sA[128*40];
  int bidx = blockIdx.x;
  int mt = bidx & 1; long nt = bidx >> 1;
  int co0 = mt*128; long p0 = nt*128;
  int bl = (int)(p0>>12), pl0 = (int)(p0&4095);
  int gb = b0 + bl;
  int tid = threadIdx.x;
  int wid=tid>>6, lane=tid&63, l16=lane&15, qd=lane>>4;
  int wm=wid>>1, wn=wid&1;
  f32x4 zf = {0.f,0.f,0.f,0.f};
  f32x4 acc[4][4];
  #pragma unroll
  for (int i=0;i<4;++i){
    #pragma unroll
    for (int j=0;j<4;++j) acc[i][j] = zf;
  }
  for (int kk=0; kk<512; kk+=32){
    __syncthreads();
    #pragma unroll
    for (int ps=0; ps<2; ++ps){
      int idx = ps*256+tid; int r = idx>>2, c8=(idx&3)*8;
      const float* wp = &Wo[(long)(co0+r)*512 + kk + c8];
      f32x4 w0 = *(const f32x4*)wp;
      f32x4 w1 = *(const f32x4*)(wp+4);
      u16x8 pw;
      #pragma unroll
      for (int u=0;u<4;++u){ pw[u]=f2b(w0[u]); pw[4+u]=f2b(w1[u]); }
      *(u16x8*)&sW[r*40+c8] = pw;
      int oc = kk + c8; int hh = oc>>6, dd = oc&63;
      *(u16x8*)&sA[r*40+c8] = *(const u16x8*)&AC[((long)(bl*8+hh)*4096 + pl0 + r)*64 + dd];
    }
    __syncthreads();
    bf16x8 a[4], bb[4];
    #pragma unroll
    for (int mi=0;mi<4;++mi) a[mi]  = ldb8(&sW[(wm*64+mi*16+l16)*40 + qd*8]);
    #pragma unroll
    for (int ni=0;ni<4;++ni) bb[ni] = ldb8(&sA[(wn*64+ni*16+l16)*40 + qd*8]);
    #pragma unroll
    for (int mi=0;mi<4;++mi){
      #pragma unroll
      for (int ni=0;ni<4;++ni)
        acc[mi][ni] = MFMA16(a[mi], bb[ni], acc[mi][ni]);
    }
  }
  #pragma unroll
  for (int mi=0;mi<4;++mi){
    #pragma unroll
    for (int ni=0;ni<4;++ni){
      int n = wn*64+ni*16+l16; int pl = pl0+n;
      #pragma unroll
      for (int r=0;r<4;++r){
        int co = co0 + wm*64+mi*16+qd*4+r;
        long addr = ((long)(gb*256+co))*4096 + pl;
        out[addr] = acc[mi][ni][r] + bo[co] + x[addr];
      }
    }
  }
}

// ---------------------------------------------------------------------------
extern "C" void kernel_launch(void* const* d_in, const int* in_sizes, int n_in,
                              void* d_out, int out_size, void* d_ws, size_t ws_size,
                              hipStream_t stream) {
  (void)in_sizes; (void)n_in; (void)out_size;
  const float* x    = (const float*)d_in[0];
  const float* pos  = (const float*)d_in[1];
  const float* Wk   = (const float*)d_in[2];
  const float* bk   = (const float*)d_in[3];
  const float* Wq   = (const float*)d_in[4];
  const float* bq   = (const float*)d_in[5];
  const float* Wv   = (const float*)d_in[6];
  const float* bv   = (const float*)d_in[7];
  const float* Wo   = (const float*)d_in[8];
  const float* bo   = (const float*)d_in[9];
  float* out = (float*)d_out;
  char* ws = (char*)d_ws;

  // Fixed: WP 786,432 + WPOS 12,288 + BIAS 3,072 = 801,792 B.
  // Per-batch: {Q,K,V,U} 4 x 4,194,304 + {M,L} 2 x 131,072 = 17,039,360 B.
  const long per_batch = 17039360l;
  const long fixed = 801792l;
  if (fixed + per_batch > (long)ws_size){
    k_sentinel<<<65536, 256, 0, stream>>>(out);
    return;
  }
  int CB = 16;
  while (CB > 1 && fixed + (long)CB*per_batch > (long)ws_size) CB >>= 1;

  u16*  WP   = (u16*)(ws);
  u16*  WPOS = (u16*)(ws + 786432l);
  u16*  BIAS = (u16*)(ws + 798720l);
  long base  = fixed;
  u16*  Qc   = (u16*)(ws + base);
  u16*  Kc   = (u16*)(ws + base + (long)CB*4194304l);
  u16*  Vc   = (u16*)(ws + base + 2l*(long)CB*4194304l);
  u16*  Uw   = (u16*)(ws + base + 3l*(long)CB*4194304l);
  float* MWc = (float*)(ws + base + 4l*(long)CB*4194304l);
  float* LWc = (float*)((char*)MWc + (long)CB*131072l);

  k_prep_w<<<1536, 256, 0, stream>>>(Wq, Wk, Wv, bq, bk, bv, WP, WPOS, BIAS);
  for (int b0 = 0; b0 < 16; b0 += CB){
    k_qkv     <<<CB*384, 256, 0, stream>>>(x, WP, WPOS, pos, BIAS, Qc, Kc, Vc, b0);
    k_attn_row<<<CB*512, 256, 0, stream>>>(Qc, Kc, Vc, Uw, MWc, LWc);
    k_attn_col<<<CB*512, 256, 0, stream>>>(Qc, Kc, Vc, Uw, MWc, LWc);
    k_oproj   <<<CB*64,  256, 0, stream>>>(Wo, bo, Uw, x, out, b0);
  }
}

// Round 6
// 429.524 us; speedup vs baseline: 1.3858x; 1.3858x over previous
//
#include <hip/hip_runtime.h>

typedef unsigned short u16;
typedef __bf16 bf16x8 __attribute__((ext_vector_type(8)));
typedef float f32x4 __attribute__((ext_vector_type(4)));
typedef unsigned short u16x8 __attribute__((ext_vector_type(8)));
typedef unsigned short u16x4 __attribute__((ext_vector_type(4)));

#define MFMA16(A,B,C) __builtin_amdgcn_mfma_f32_16x16x32_bf16(A,B,C,0,0,0)

__device__ __forceinline__ float b2f(u16 h){ unsigned u = ((unsigned)h)<<16; return __builtin_bit_cast(float,u); }
__device__ __forceinline__ u16 f2b(float f){ unsigned u = __builtin_bit_cast(unsigned,f); u += 0x7fffu + ((u>>16)&1u); return (u16)(u>>16); }
__device__ __forceinline__ bf16x8 ldb8(const u16* p){ return __builtin_bit_cast(bf16x8, *(const u16x8*)p); }

// async global->LDS, 16B per lane; LDS dest = wave-uniform base + lane*16.
__device__ __forceinline__ void g2lds16(const u16* g, u16* l){
  __builtin_amdgcn_global_load_lds((const __attribute__((address_space(1))) void*)g,
                                   (__attribute__((address_space(3))) void*)l, 16, 0, 0);
}

// B=16, C=256, H=W=64, NH=8, DH=64, POS_C=4.  4096 px/batch.
// fp32 inputs/output; bf16 internal.  CB batches/chunk from ws_size
// (R5 counters prove ws >= 273 MB -> CB >= 8).
// Layouts: XT [p][c] bf16; Q,K [bl][h][p][d]; Vt [bl][h][d][p];
// Vtc [bl][h][d][pT] (pT = (p&63)*64 + (p>>6)); U [bl][h][p][d].

// ---------------------------------------------------------------------------
// Weight prep: WP[1536][256], WPOS[1536][4], BIAS[1536], WoP[256][512] (bf16).
__global__ void k_prep_w(const float* __restrict__ Wq, const float* __restrict__ Wk,
                         const float* __restrict__ Wv, const float* __restrict__ bq,
                         const float* __restrict__ bk, const float* __restrict__ bv,
                         const float* __restrict__ Wo,
                         u16* __restrict__ WP, u16* __restrict__ WPOS,
                         u16* __restrict__ BIAS, u16* __restrict__ WoP){
  int r = blockIdx.x;                 // 0..1791
  int tid = threadIdx.x;
  if (r < 1536){
    int t = r >> 9, rm = r & 511;
    const float* src = (t==0 ? Wq : (t==1 ? Wk : Wv)) + (long)rm*260;
    WP[(long)r*256 + tid] = f2b(src[tid]);
    if (tid < 4) WPOS[r*4 + tid] = f2b(src[256 + tid]);
    if (tid == 0){
      const float* bs = (t==0 ? bq : (t==1 ? bk : bv));
      BIAS[r] = f2b(bs[rm]);
    }
  } else {
    int co = r - 1536;
    WoP[(long)co*512 + tid]       = f2b(Wo[(long)co*512 + tid]);
    WoP[(long)co*512 + 256 + tid] = f2b(Wo[(long)co*512 + 256 + tid]);
  }
}

// Diagnostic: ws too small -> fill out with 100.0f.
__global__ void k_sentinel(float* __restrict__ out){
  long i = (long)blockIdx.x*256 + threadIdx.x;
  out[i] = 100.0f;
}

// ---------------------------------------------------------------------------
// x [gb][c][4096] fp32 -> XT [bl*4096+p][256] bf16 (transpose + convert).
__global__ __launch_bounds__(256) void k_cvtx(const float* __restrict__ x,
                                              u16* __restrict__ XT, int b0){
  __shared__ u16 tile[64*65];
  int bidx = blockIdx.x;
  int ct = bidx & 3, pt = (bidx>>2)&63, bl = bidx>>8;
  int c0 = ct*64, p0 = pt*64;
  int tid = threadIdx.x;
  const float* xb = x + (long)(b0+bl)*256*4096;
  #pragma unroll
  for (int it=0; it<16; ++it){
    int idx = it*256 + tid; int cc = idx>>6, px = idx&63;
    tile[cc*65 + px] = f2b(xb[(long)(c0+cc)*4096 + p0 + px]);
  }
  __syncthreads();
  u16* dst = XT + ((long)(bl*4096 + p0))*256 + c0;
  #pragma unroll
  for (int it=0; it<4; ++it){
    int idx = it*256 + tid; int pp = idx>>4, c4 = (idx&15)*4;
    u16x4 o;
    #pragma unroll
    for (int u=0;u<4;++u) o[u] = tile[(c4+u)*65 + pp];
    *(u16x4*)&dst[(long)pp*256 + c4] = o;
  }
}

// ---------------------------------------------------------------------------
// QKV GEMM (m97-style): M=1536 (oc), N=CB*4096 (px), K=256 (+pos rank-4 epi).
// global_load_lds staging into unpadded [128][32] tiles.
__global__ __launch_bounds__(256) void k_qkv(
    const u16* __restrict__ XT, const u16* __restrict__ WP,
    const u16* __restrict__ WPOS, const float* __restrict__ pos,
    const u16* __restrict__ BIAS,
    u16* __restrict__ Qb, u16* __restrict__ Kb, u16* __restrict__ Vt){
  __shared__ u16 sW[128*32];
  __shared__ u16 sX[128*32];
  __shared__ u16 sPW[512];     // [oc_r][4]
  __shared__ u16 sPP[512];     // [c][128]
  int bidx = blockIdx.x;
  int mt = bidx % 12; long nt = bidx / 12;
  int oc0 = mt*128; long p0 = nt*128;
  int bl = (int)(p0>>12); int pl0 = (int)(p0 & 4095);
  int tid = threadIdx.x;
  for (int k = tid; k < 512; k += 256) sPW[k] = WPOS[(long)oc0*4 + k];
  for (int k = tid; k < 512; k += 256){ int c = k>>7, p = k&127; sPP[k] = f2b(pos[(long)c*4096 + pl0 + p]); }
  f32x4 zf = {0.f,0.f,0.f,0.f};
  f32x4 acc[4][4];
  #pragma unroll
  for (int i=0;i<4;++i){
    #pragma unroll
    for (int j=0;j<4;++j) acc[i][j] = zf;
  }
  int wid = tid>>6, lane = tid&63, l16 = lane&15, qd = lane>>4;
  int wm = wid>>1, wn = wid&1;
  int srow = lane>>2, sc8 = (lane&3)*8;
  for (int kk = 0; kk < 256; kk += 32){
    __syncthreads();
    #pragma unroll
    for (int c=0;c<2;++c){
      int seg = wid*2 + c;                 // 0..7, wave-uniform
      int row = seg*16 + srow;
      g2lds16(&WP[(long)(oc0+row)*256 + kk + sc8], &sW[seg*512]);
      g2lds16(&XT[(p0 + row)*256 + kk + sc8],      &sX[seg*512]);
    }
    __syncthreads();
    bf16x8 a[4], bb[4];
    #pragma unroll
    for (int mi=0;mi<4;++mi) a[mi]  = ldb8(&sW[(wm*64+mi*16+l16)*32 + qd*8]);
    #pragma unroll
    for (int ni=0;ni<4;++ni) bb[ni] = ldb8(&sX[(wn*64+ni*16+l16)*32 + qd*8]);
    #pragma unroll
    for (int mi=0;mi<4;++mi){
      #pragma unroll
      for (int ni=0;ni<4;++ni)
        acc[mi][ni] = MFMA16(a[mi], bb[ni], acc[mi][ni]);
    }
  }
  // epilogue: + pos rank-4 + bias.  Q,K -> [p][d]; V -> Vt [d][p].
  #pragma unroll
  for (int mi=0;mi<4;++mi){
    int mbase = wm*64 + mi*16 + qd*4;
    int ocb = oc0 + mbase;
    int t = ocb>>9, ocm = ocb&511;
    int hh = ocm>>6, dd = ocm&63;
    #pragma unroll
    for (int ni=0;ni<4;++ni){
      int n = wn*64 + ni*16 + l16;
      int pl = pl0 + n;
      float pv[4];
      #pragma unroll
      for (int r=0;r<4;++r){
        float v = acc[mi][ni][r];
        #pragma unroll
        for (int c=0;c<4;++c) v += b2f(sPW[(mbase+r)*4+c]) * b2f(sPP[c*128 + n]);
        pv[r] = v + b2f(BIAS[ocb + r]);
      }
      if (t < 2){
        u16* dstb = (t==0? Qb : Kb);
        u16x4 pk;
        #pragma unroll
        for (int r=0;r<4;++r) pk[r] = f2b(pv[r]);
        *(u16x4*)&dstb[((long)(bl*8+hh)*4096 + pl)*64 + dd] = pk;
      } else {
        long base = (long)(bl*8+hh)*262144 + (long)dd*4096 + pl;
        #pragma unroll
        for (int r=0;r<4;++r) Vt[base + (long)r*4096] = f2b(pv[r]);
      }
    }
  }
}

// ---------------------------------------------------------------------------
// Pixel-grid transpose: Vtc[ph][d][j*64+i] = Vt[ph][d][i*64+j].
__global__ __launch_bounds__(256) void k_vtr(const u16* __restrict__ Vt,
                                             u16* __restrict__ Vtc){
  __shared__ u16 tile[64*68];
  int bid = blockIdx.x;
  int d = bid & 63; long ph = bid >> 6;
  const u16* src = Vt + ph*262144 + (long)d*4096;
  u16* dst = Vtc + ph*262144 + (long)d*4096;
  int tid = threadIdx.x;
  #pragma unroll
  for (int it=0; it<2; ++it){
    int idx = it*256 + tid; int i = idx>>3, j8 = (idx&7)*8;
    u16x8 v = *(const u16x8*)&src[i*64 + j8];
    u16x4 lo = {v[0],v[1],v[2],v[3]}, hi = {v[4],v[5],v[6],v[7]};
    *(u16x4*)&tile[i*68 + j8]     = lo;
    *(u16x4*)&tile[i*68 + j8 + 4] = hi;
  }
  __syncthreads();
  #pragma unroll
  for (int it=0; it<2; ++it){
    int idx = it*256 + tid; int j = idx>>3, i8 = (idx&7)*8;
    u16x8 o;
    #pragma unroll
    for (int u=0;u<8;++u) o[u] = tile[(i8+u)*68 + j];
    *(u16x8*)&dst[j*64 + i8] = o;
  }
}

// ---------------------------------------------------------------------------
// Axial attention pass.  COL=0: rows (block (bl,h,i)), writes unnormalized
// U + fp32 m,l.  COL=1: cols (block (bl,h,j)), local stats in-register,
// flash-merges with row results, overwrites U with final A.
// V source pre-transposed (Vt for rows, Vtc for cols) -> pure vector staging.
template<int COL>
__global__ __launch_bounds__(256) void k_attn(
    const u16* __restrict__ Qb, const u16* __restrict__ Kb,
    const u16* __restrict__ Vsrc, u16* __restrict__ U,
    float* __restrict__ M, float* __restrict__ L){
  __shared__ u16 sm[4*64*72];
  u16* Qs = sm;            // [line][d]  stride 72
  u16* Ks = sm + 4608;
  u16* VT = sm + 9216;     // [d][key]
  u16* Ps = sm + 13824;    // [q][k]
  int bid = blockIdx.x;
  int rc = bid&63, h=(bid>>6)&7, bl=bid>>9;
  long plane  = (long)(bl*8+h)*262144;
  long sbase  = (long)(bl*8+h)*4096;
  int tid = threadIdx.x;
  #pragma unroll
  for (int it=0; it<2; ++it){
    int idx = it*256 + tid; int row = idx>>3, c8 = (idx&7)*8;
    long gqk = plane + ((long)(COL ? (row*64 + rc) : (rc*64 + row)))*64 + c8;
    *(u16x8*)&Qs[row*72 + c8] = *(const u16x8*)&Qb[gqk];
    *(u16x8*)&Ks[row*72 + c8] = *(const u16x8*)&Kb[gqk];
    long gv = plane + (long)row*4096 + rc*64 + c8;   // row == d here
    *(u16x8*)&VT[row*72 + c8] = *(const u16x8*)&Vsrc[gv];
  }
  __syncthreads();
  int wid = tid>>6, lane = tid&63, l16 = lane&15, qd = lane>>4;
  int j0 = wid*16;
  f32x4 zf = {0.f,0.f,0.f,0.f};
  f32x4 sv[4] = {zf,zf,zf,zf};
  #pragma unroll
  for (int d0=0; d0<64; d0+=32){
    bf16x8 a = ldb8(&Qs[(j0+l16)*72 + d0 + qd*8]);
    #pragma unroll
    for (int n=0;n<4;++n){
      bf16x8 bb = ldb8(&Ks[(n*16+l16)*72 + d0 + qd*8]);
      sv[n] = MFMA16(a, bb, sv[n]);
    }
  }
  const float scale = 0.08838834764831845f;   // 1/sqrt(128)
  float mrow[4], lrow[4];
  #pragma unroll
  for (int r=0;r<4;++r){
    float mv = -1e30f;
    #pragma unroll
    for (int n=0;n<4;++n){ sv[n][r] *= scale; mv = fmaxf(mv, sv[n][r]); }
    mv = fmaxf(mv, __shfl_xor(mv,1)); mv = fmaxf(mv, __shfl_xor(mv,2));
    mv = fmaxf(mv, __shfl_xor(mv,4)); mv = fmaxf(mv, __shfl_xor(mv,8));
    float ls = 0.f;
    #pragma unroll
    for (int n=0;n<4;++n){ float p = expf(fminf(sv[n][r]-mv, 0.f)); sv[n][r] = p; ls += p; }
    ls += __shfl_xor(ls,1); ls += __shfl_xor(ls,2);
    ls += __shfl_xor(ls,4); ls += __shfl_xor(ls,8);
    mrow[r]=mv; lrow[r]=ls;
    int qi = j0 + qd*4 + r;
    #pragma unroll
    for (int n=0;n<4;++n) Ps[qi*72 + n*16 + l16] = f2b(sv[n][r]);
  }
  __syncthreads();
  f32x4 u4[4] = {zf,zf,zf,zf};
  #pragma unroll
  for (int k0=0;k0<64;k0+=32){
    bf16x8 a = ldb8(&Ps[(j0+l16)*72 + k0 + qd*8]);
    #pragma unroll
    for (int n=0;n<4;++n){
      bf16x8 bb = ldb8(&VT[(n*16+l16)*72 + k0 + qd*8]);
      u4[n] = MFMA16(a, bb, u4[n]);
    }
  }
  if (!COL){
    #pragma unroll
    for (int r=0;r<4;++r){
      int qi = j0 + qd*4 + r;
      long pl = (long)rc*64 + qi;
      long ob = (sbase + pl)*64;
      #pragma unroll
      for (int n=0;n<4;++n) U[ob + n*16 + l16] = f2b(u4[n][r]);
      if (l16==0){ M[sbase+pl]=mrow[r]; L[sbase+pl]=lrow[r]; }
    }
  } else {
    #pragma unroll
    for (int r=0;r<4;++r){
      int qi = j0 + qd*4 + r;
      long pix = sbase + (long)qi*64 + rc;
      float mw = M[pix], lw = L[pix];
      float mh = mrow[r], lh = lrow[r];
      float m  = fmaxf(mw, mh);
      float ew = expf(fminf(mw - m, 0.f));
      float eh = expf(fminf(mh - m, 0.f));
      float rden = 1.f / fmaxf(ew*lw + eh*lh, 1e-20f);
      long ob = pix*64;
      #pragma unroll
      for (int n=0;n<4;++n){
        float uw = b2f(U[ob + n*16 + l16]);
        U[ob + n*16 + l16] = f2b((ew*uw + eh*u4[n][r])*rden);
      }
    }
  }
}

// ---------------------------------------------------------------------------
// Output projection + residual (m97-style staging): out = x + Wo @ A + bo.
// M=256 (co), N=CB*4096 (px), K=512.  A in U [bl][h][p][d] bf16.
__global__ __launch_bounds__(256) void k_oproj(
    const u16* __restrict__ WoP, const float* __restrict__ bo,
    const u16* __restrict__ AC, const float* __restrict__ x,
    float* __restrict__ out, int b0){
  __shared__ u16 sW[128*32];
  __shared__ u16 sA[128*32];
  int bidx = blockIdx.x;
  int mt = bidx & 1; long nt = bidx >> 1;
  int co0 = mt*128; long p0 = nt*128;
  int bl = (int)(p0>>12), pl0 = (int)(p0&4095);
  int gb = b0 + bl;
  int tid = threadIdx.x;
  int wid=tid>>6, lane=tid&63, l16=lane&15, qd=lane>>4;
  int wm=wid>>1, wn=wid&1;
  int srow = lane>>2, sc8 = (lane&3)*8;
  f32x4 zf = {0.f,0.f,0.f,0.f};
  f32x4 acc[4][4];
  #pragma unroll
  for (int i=0;i<4;++i){
    #pragma unroll
    for (int j=0;j<4;++j) acc[i][j] = zf;
  }
  for (int kk=0; kk<512; kk+=32){
    __syncthreads();
    #pragma unroll
    for (int c=0;c<2;++c){
      int seg = wid*2 + c;
      int row = seg*16 + srow;
      g2lds16(&WoP[(long)(co0+row)*512 + kk + sc8], &sW[seg*512]);
      g2lds16(&AC[((long)(bl*8+(kk>>6))*4096 + pl0 + row)*64 + (kk&63) + sc8], &sA[seg*512]);
    }
    __syncthreads();
    bf16x8 a[4], bb[4];
    #pragma unroll
    for (int mi=0;mi<4;++mi) a[mi]  = ldb8(&sW[(wm*64+mi*16+l16)*32 + qd*8]);
    #pragma unroll
    for (int ni=0;ni<4;++ni) bb[ni] = ldb8(&sA[(wn*64+ni*16+l16)*32 + qd*8]);
    #pragma unroll
    for (int mi=0;mi<4;++mi){
      #pragma unroll
      for (int ni=0;ni<4;++ni)
        acc[mi][ni] = MFMA16(a[mi], bb[ni], acc[mi][ni]);
    }
  }
  #pragma unroll
  for (int mi=0;mi<4;++mi){
    #pragma unroll
    for (int ni=0;ni<4;++ni){
      int n = wn*64+ni*16+l16; int pl = pl0+n;
      #pragma unroll
      for (int r=0;r<4;++r){
        int co = co0 + wm*64+mi*16+qd*4+r;
        long addr = ((long)(gb*256+co))*4096 + pl;
        out[addr] = acc[mi][ni][r] + bo[co] + x[addr];
      }
    }
  }
}

// ---------------------------------------------------------------------------
extern "C" void kernel_launch(void* const* d_in, const int* in_sizes, int n_in,
                              void* d_out, int out_size, void* d_ws, size_t ws_size,
                              hipStream_t stream) {
  (void)in_sizes; (void)n_in; (void)out_size;
  const float* x    = (const float*)d_in[0];
  const float* pos  = (const float*)d_in[1];
  const float* Wk   = (const float*)d_in[2];
  const float* bk   = (const float*)d_in[3];
  const float* Wq   = (const float*)d_in[4];
  const float* bq   = (const float*)d_in[5];
  const float* Wv   = (const float*)d_in[6];
  const float* bv   = (const float*)d_in[7];
  const float* Wo   = (const float*)d_in[8];
  const float* bo   = (const float*)d_in[9];
  float* out = (float*)d_out;
  char* ws = (char*)d_ws;

  // Fixed: WP 786,432 + WPOS 12,288 + BIAS 3,072 + WoP 262,144 = 1,063,936 B.
  // Per-batch: XT 2,097,152 + {Q,K,Vt,Vtc,U} 5 x 4,194,304 + {M,L} 2 x 131,072
  //          = 23,330,816 B.   (R5 counters prove ws >= 273 MB -> CB >= 8.)
  const long per_batch = 23330816l;
  const long fixed = 1063936l;
  if (fixed + per_batch > (long)ws_size){
    k_sentinel<<<65536, 256, 0, stream>>>(out);
    return;
  }
  int CB = 16;
  while (CB > 1 && fixed + (long)CB*per_batch > (long)ws_size) CB >>= 1;

  u16*  WP   = (u16*)(ws);
  u16*  WPOS = (u16*)(ws + 786432l);
  u16*  BIAS = (u16*)(ws + 798720l);
  u16*  WoP  = (u16*)(ws + 801792l);
  long base  = fixed;
  u16*  XT   = (u16*)(ws + base);
  u16*  Qc   = (u16*)(ws + base + (long)CB*2097152l);
  u16*  Kc   = (u16*)((char*)Qc  + (long)CB*4194304l);
  u16*  Vt   = (u16*)((char*)Kc  + (long)CB*4194304l);
  u16*  Vtc  = (u16*)((char*)Vt  + (long)CB*4194304l);
  u16*  Uw   = (u16*)((char*)Vtc + (long)CB*4194304l);
  float* MWc = (float*)((char*)Uw + (long)CB*4194304l);
  float* LWc = (float*)((char*)MWc + (long)CB*131072l);

  k_prep_w<<<1792, 256, 0, stream>>>(Wq, Wk, Wv, bq, bk, bv, Wo, WP, WPOS, BIAS, WoP);
  for (int b0 = 0; b0 < 16; b0 += CB){
    k_cvtx    <<<CB*256, 256, 0, stream>>>(x, XT, b0);
    k_qkv     <<<CB*384, 256, 0, stream>>>(XT, WP, WPOS, pos, BIAS, Qc, Kc, Vt);
    k_vtr     <<<CB*512, 256, 0, stream>>>(Vt, Vtc);
    k_attn<0> <<<CB*512, 256, 0, stream>>>(Qc, Kc, Vt,  Uw, MWc, LWc);
    k_attn<1> <<<CB*512, 256, 0, stream>>>(Qc, Kc, Vtc, Uw, MWc, LWc);
    k_oproj   <<<CB*64,  256, 0, stream>>>(WoP, bo, Uw, x, out, b0);
  }
}